// Round 1
// baseline (4701.607 us; speedup 1.0000x reference)
//
#include <hip/hip_runtime.h>
#include <cstdint>
#include <cstddef>

#define DIM_D 32
#define DIM_X 65
#define KIN   66      // DIM_X + 1 (x ++ time)
#define KPAD  68
#define DIM_H 256
#define NSTE  100
#define BATCHN 4096
#define ROWS  16
#define BLKT  512
#define NBLK  (BATCHN / ROWS)   // 256
#define RPT   8                 // rows per thread in GEMM phases

// JAX threefry mode: 1 = partitionable (modern default), 0 = legacy split-iota
#define TF_PARTITIONABLE 1

constexpr float DT_C = 0.01f;

#define CTRL_OFF 0
#define X_OFF ((size_t)BATCHN * NSTE * DIM_D)                    // 13107200
#define J_OFF (X_OFF + (size_t)BATCHN * NSTE * DIM_X)            // +26624000

__device__ __forceinline__ uint32_t rotl32(uint32_t x, int n) {
  return (x << n) | (x >> (32 - n));
}

// Threefry-2x32, 20 rounds — matches jax/_src/prng.py _threefry2x32_lowering
__device__ __forceinline__ void tf2x32(uint32_t k0, uint32_t k1,
                                       uint32_t x0, uint32_t x1,
                                       uint32_t& o0, uint32_t& o1) {
  uint32_t k2 = k0 ^ k1 ^ 0x1BD11BDAu;
#define TFR(r) { x0 += x1; x1 = rotl32(x1, (r)); x1 ^= x0; }
  x0 += k0; x1 += k1;
  TFR(13) TFR(15) TFR(26) TFR(6)   x0 += k1; x1 += k2 + 1u;
  TFR(17) TFR(29) TFR(16) TFR(24)  x0 += k2; x1 += k0 + 2u;
  TFR(13) TFR(15) TFR(26) TFR(6)   x0 += k0; x1 += k1 + 3u;
  TFR(17) TFR(29) TFR(16) TFR(24)  x0 += k1; x1 += k2 + 4u;
  TFR(13) TFR(15) TFR(26) TFR(6)   x0 += k2; x1 += k0 + 5u;
#undef TFR
  o0 = x0; o1 = x1;
}

// z_out[r][h] = relu(b[h] + sum_k z_in[r][k] * W[h][k]),  W row-major [256][256]
__device__ __forceinline__ void layer_hh(const float* __restrict__ W,
                                         const float* __restrict__ b,
                                         const float (*__restrict__ zin)[DIM_H],
                                         float (*__restrict__ zout)[DIM_H],
                                         int h, int rbase) {
  float acc[RPT];
  const float bb = b[h];
#pragma unroll
  for (int r = 0; r < RPT; ++r) acc[r] = bb;
  const float4* wr = (const float4*)(W + (size_t)h * DIM_H);
#pragma unroll 2
  for (int k4 = 0; k4 < DIM_H / 4; ++k4) {
    const float4 w = wr[k4];
#pragma unroll
    for (int r = 0; r < RPT; ++r) {
      const float4 z = *(const float4*)(&zin[rbase + r][k4 * 4]);
      acc[r] += z.x * w.x;
      acc[r] += z.y * w.y;
      acc[r] += z.z * w.z;
      acc[r] += z.w * w.w;
    }
  }
#pragma unroll
  for (int r = 0; r < RPT; ++r) zout[rbase + r][h] = fmaxf(acc[r], 0.0f);
}

__global__ __launch_bounds__(BLKT, 2) void model_kernel(
    const float* __restrict__ W1, const float* __restrict__ b1,
    const float* __restrict__ W2, const float* __restrict__ b2,
    const float* __restrict__ W3, const float* __restrict__ b3,
    const float* __restrict__ W4, const float* __restrict__ b4,
    const float* __restrict__ x0p, const float* __restrict__ sp,
    const float* __restrict__ dpp, float* __restrict__ out)
{
  __shared__ float inA[ROWS][KPAD];     // current x (V[32], Dv, CR[32]) ++ t at [65]
  __shared__ float zA[ROWS][DIM_H];
  __shared__ float zB[ROWS][DIM_H];
  __shared__ float hVl[ROWS][DIM_D];
  __shared__ float hDl[ROWS];
  __shared__ float fl[ROWS];
  __shared__ float s_sh[DIM_D];
  __shared__ float dp_sh;
  __shared__ uint32_t keys[NSTE - 1][2];

  const int tid = threadIdx.x;
  const int r0  = blockIdx.x * ROWS;

  // ---------------- init ----------------
  if (tid < NSTE - 1) {
    uint32_t o0, o1;
    tf2x32(0u, 1234u, 0u, (uint32_t)tid, o0, o1);   // fold_in(key(1234), n)
    keys[tid][0] = o0; keys[tid][1] = o1;
  }
  if (tid < DIM_D) s_sh[tid] = sp[tid];
  if (tid == 0)    dp_sh = dpp[0];
  __syncthreads();  // s_sh / dp_sh ready

  for (int i = tid; i < ROWS * DIM_X; i += BLKT) {
    int r = i / DIM_X, c = i % DIM_X;
    float v = x0p[c];
    inA[r][c] = v;
    out[X_OFF + (size_t)(r0 + r) * NSTE * DIM_X + c] = v;        // x_tensor[:,0,:]
  }
  for (int i = tid; i < ROWS * DIM_D; i += BLKT) {
    int r = i / DIM_D, d = i % DIM_D;
    hVl[r][d] = -logf(1.0f - x0p[d]) / s_sh[d];
    out[CTRL_OFF + (size_t)(r0 + r) * NSTE * DIM_D + (size_t)(NSTE - 1) * DIM_D + d] = 0.0f;
  }
  if (tid < ROWS) {
    hDl[tid] = x0p[DIM_D] / dp_sh;
    fl[tid]  = 0.0f;
    inA[tid][DIM_X] = 0.0f;        // t = 0
    inA[tid][66] = 0.0f; inA[tid][67] = 0.0f;
  }
  __syncthreads();

  const int h     = tid & (DIM_H - 1);
  const int rbase = (tid >> 8) * RPT;   // 0 or 8

  for (int n = 0; n < NSTE - 1; ++n) {
    // ---- Layer 1: inA(66) -> zA ----
    {
      float acc[RPT];
      const float bb = b1[h];
#pragma unroll
      for (int r = 0; r < RPT; ++r) acc[r] = bb;
      const float* wr = W1 + (size_t)h * KIN;
      for (int k = 0; k < KIN; k += 2) {
        float w0 = wr[k], w1 = wr[k + 1];
#pragma unroll
        for (int r = 0; r < RPT; ++r)
          acc[r] += inA[rbase + r][k] * w0 + inA[rbase + r][k + 1] * w1;
      }
#pragma unroll
      for (int r = 0; r < RPT; ++r) zA[rbase + r][h] = fmaxf(acc[r], 0.0f);
    }
    __syncthreads();
    // ---- Layer 2: zA -> zB ----
    layer_hh(W2, b2, zA, zB, h, rbase);
    __syncthreads();
    // ---- Layer 3: zB -> zA ----
    layer_hh(W3, b3, zB, zA, h, rbase);
    __syncthreads();

    // ---- Layer 4 (each thread: one (r,d)) + f accumulation with OLD x ----
    float u;
    {
      const int r = tid >> 5, d = tid & 31;
      float acc = b4[d];
      const float4* wr4 = (const float4*)(W4 + (size_t)d * DIM_H);
      const float4* z4  = (const float4*)(&zA[r][0]);
#pragma unroll 4
      for (int k4 = 0; k4 < DIM_H / 4; ++k4) {
        const float4 w = wr4[k4];
        const float4 z = z4[k4];
        acc += z.x * w.x + z.y * w.y + z.z * w.z + z.w * w.w;
      }
      u = 1.0f / (1.0f + expf(-acc));
      out[CTRL_OFF + (size_t)(r0 + r) * NSTE * DIM_D + (size_t)n * DIM_D + d] = u;
    }
    if (tid < ROWS) {
      float sum = 0.0f;
#pragma unroll
      for (int d = 0; d < DIM_D; ++d) sum += inA[tid][d];
      fl[tid] += sum * DT_C;    // f += sum(x[:, :D]) * DT  (pre-update x)
    }
    __syncthreads();

    // ---- state update ----
    {
      const int r = tid >> 5, d = tid & 31;
      const uint32_t F = (uint32_t)((r0 + r) * DIM_D + d);
      const uint32_t k0 = keys[n][0], k1 = keys[n][1];
      uint32_t o0, o1, bits;
#if TF_PARTITIONABLE
      tf2x32(k0, k1, 0u, F, o0, o1);
      bits = o0 ^ o1;
#else
      const uint32_t half = (uint32_t)(BATCHN * DIM_D / 2);
      if (F < half) { tf2x32(k0, k1, F, F + half, o0, o1); bits = o0; }
      else          { tf2x32(k0, k1, F - half, F, o0, o1); bits = o1; }
#endif
      const float uf = __uint_as_float((bits >> 9) | 0x3f800000u) - 1.0f;
      const bool jump = uf < 0.05f;

      float hv = jump ? 0.0f : (hVl[r][d] + DT_C);
      hVl[r][d] = hv;
      float cr = inA[r][DIM_D + 1 + d] + (jump ? u : 0.0f);
      float V  = 1.0f - expf(-s_sh[d] * hv);
      inA[r][d] = V;
      inA[r][DIM_D + 1 + d] = cr;

      const size_t xb = X_OFF + (size_t)(r0 + r) * NSTE * DIM_X + (size_t)(n + 1) * DIM_X;
      out[xb + d] = V;
      out[xb + DIM_D + 1 + d] = cr;
      if (d == 0) {
        float hd = hDl[r] + DT_C;
        hDl[r] = hd;
        float Dv = dp_sh * hd;
        inA[r][DIM_D] = Dv;
        inA[r][DIM_X] = DT_C * (float)(n + 1);   // t for next step
        out[xb + DIM_D] = Dv;
      }
    }
    __syncthreads();
  }

  // ---- J = f + sum(x_last CR) ----
  if (tid < ROWS) {
    float s = 0.0f;
#pragma unroll
    for (int d = 0; d < DIM_D; ++d) s += inA[tid][DIM_D + 1 + d];
    out[J_OFF + (size_t)(r0 + tid)] = fl[tid] + s;
  }
}

extern "C" void kernel_launch(void* const* d_in, const int* in_sizes, int n_in,
                              void* d_out, int out_size, void* d_ws, size_t ws_size,
                              hipStream_t stream) {
  const float* W1 = (const float*)d_in[0];
  const float* b1 = (const float*)d_in[1];
  const float* W2 = (const float*)d_in[2];
  const float* b2 = (const float*)d_in[3];
  const float* W3 = (const float*)d_in[4];
  const float* b3 = (const float*)d_in[5];
  const float* W4 = (const float*)d_in[6];
  const float* b4 = (const float*)d_in[7];
  const float* x0 = (const float*)d_in[8];
  const float* s  = (const float*)d_in[9];
  const float* dp = (const float*)d_in[10];
  float* out = (float*)d_out;
  hipLaunchKernelGGL(model_kernel, dim3(NBLK), dim3(BLKT), 0, stream,
                     W1, b1, W2, b2, W3, b3, W4, b4, x0, s, dp, out);
}

// Round 2
// 260.431 us; speedup vs baseline: 18.0532x; 18.0532x over previous
//
#include <hip/hip_runtime.h>
#include <cstdint>
#include <cstddef>

#define DIM_D 32
#define KIN   66
#define DIM_H 256
#define NSTE  100
#define BATCHN 4096
#define ROWS  16
#define BLKT  512
#define NBLK  (BATCHN / ROWS)   // 256

#define CTRL_OFF 0
#define X_OFF ((size_t)BATCHN * NSTE * DIM_D)
#define J_OFF (X_OFF + (size_t)BATCHN * NSTE * 65)

// bf16 weight arrays in d_ws (element offsets)
#define W1B_OFF 0            // [256][96] (cols 66..95 zero)
#define W2B_OFF 24576        // [256][256]
#define W3B_OFF 90112        // [256][256]
#define W4B_OFF 155648       // [32][256]
#define WS_ELEMS 163840

constexpr float DT_C = 0.01f;

typedef __bf16 bf16x8 __attribute__((ext_vector_type(8)));
typedef float  f32x4  __attribute__((ext_vector_type(4)));

__device__ __forceinline__ uint32_t rotl32(uint32_t x, int n) {
  return (x << n) | (x >> (32 - n));
}

// Threefry-2x32, 20 rounds — matches jax partitionable path (verified round 1)
__device__ __forceinline__ void tf2x32(uint32_t k0, uint32_t k1,
                                       uint32_t x0, uint32_t x1,
                                       uint32_t& o0, uint32_t& o1) {
  uint32_t k2 = k0 ^ k1 ^ 0x1BD11BDAu;
#define TFR(r) { x0 += x1; x1 = rotl32(x1, (r)); x1 ^= x0; }
  x0 += k0; x1 += k1;
  TFR(13) TFR(15) TFR(26) TFR(6)   x0 += k1; x1 += k2 + 1u;
  TFR(17) TFR(29) TFR(16) TFR(24)  x0 += k2; x1 += k0 + 2u;
  TFR(13) TFR(15) TFR(26) TFR(6)   x0 += k0; x1 += k1 + 3u;
  TFR(17) TFR(29) TFR(16) TFR(24)  x0 += k1; x1 += k2 + 4u;
  TFR(13) TFR(15) TFR(26) TFR(6)   x0 += k2; x1 += k0 + 5u;
#undef TFR
  o0 = x0; o1 = x1;
}

__global__ void conv_w(const float* __restrict__ W1, const float* __restrict__ W2,
                       const float* __restrict__ W3, const float* __restrict__ W4,
                       __bf16* __restrict__ ws) {
  int t = blockIdx.x * 256 + threadIdx.x;
  if (t < W2B_OFF) {
    int r = t / 96, c = t % 96;
    ws[t] = (c < KIN) ? (__bf16)W1[r * KIN + c] : (__bf16)0.0f;
  } else if (t < W3B_OFF) {
    ws[t] = (__bf16)W2[t - W2B_OFF];
  } else if (t < W4B_OFF) {
    ws[t] = (__bf16)W3[t - W3B_OFF];
  } else if (t < WS_ELEMS) {
    ws[t] = (__bf16)W4[t - W4B_OFF];
  }
}

__device__ __forceinline__ f32x4 mfma16(bf16x8 a, bf16x8 b, f32x4 c) {
  return __builtin_amdgcn_mfma_f32_16x16x32_bf16(a, b, c, 0, 0, 0);
}

// XOR-swizzled LDS byte offsets (write and read use the same function)
__device__ __forceinline__ int swz256(int row, int col) { return row * 256 + (col ^ ((row & 15) << 4)); }
__device__ __forceinline__ int swz512(int row, int col) { return row * 512 + (col ^ ((row & 15) << 4)); }

__global__ __launch_bounds__(BLKT, 2) void model_kernel(
    const __bf16* __restrict__ ws,
    const float* __restrict__ b1, const float* __restrict__ b2,
    const float* __restrict__ b3, const float* __restrict__ b4,
    const float* __restrict__ x0p, const float* __restrict__ sp,
    const float* __restrict__ dpp, float* __restrict__ out)
{
  __shared__ __bf16 xb[ROWS * 128];       // MLP input x (bf16, swizzled), 256B/row
  __shared__ __bf16 actA[ROWS * 256];     // 512B/row, swizzled
  __shared__ __bf16 actB[ROWS * 256];
  __shared__ float  psum[8][16][16];      // layer-4 K-split partials
  __shared__ float  xVf[ROWS][DIM_D];     // fp32 V state (for f / exact outputs)
  __shared__ float  crf[ROWS][DIM_D];     // fp32 CR state
  __shared__ float  hVl[ROWS][DIM_D];
  __shared__ float  hDl[ROWS], fl[ROWS];
  __shared__ float  s_sh[DIM_D];
  __shared__ float  dp_sh;
  __shared__ uint32_t keys[NSTE - 1][2];

  const int tid = threadIdx.x;
  const int r0  = blockIdx.x * ROWS;
  char* xbB = (char*)xb;
  char* aAB = (char*)actA;
  char* aBB = (char*)actB;

  // ---------------- init ----------------
  if (tid < NSTE - 1) {
    uint32_t o0, o1;
    tf2x32(0u, 1234u, 0u, (uint32_t)tid, o0, o1);
    keys[tid][0] = o0; keys[tid][1] = o1;
  }
  if (tid < DIM_D) s_sh[tid] = sp[tid];
  if (tid == 0)    dp_sh = dpp[0];
  for (int i = tid; i < ROWS * 128; i += BLKT) xb[i] = (__bf16)0.0f;
  __syncthreads();

  for (int i = tid; i < ROWS * KIN; i += BLKT) {
    int r = i / KIN, c = i % KIN;
    float v = (c < 65) ? x0p[c] : 0.0f;     // col 65 = t = 0
    *(__bf16*)(xbB + swz256(r, c * 2)) = (__bf16)v;
    if (c < 65) out[X_OFF + (size_t)(r0 + r) * NSTE * 65 + c] = v;
  }
  for (int i = tid; i < ROWS * DIM_D; i += BLKT) {
    int r = i / DIM_D, d = i % DIM_D;
    xVf[r][d] = x0p[d];
    crf[r][d] = x0p[33 + d];
    hVl[r][d] = -logf(1.0f - x0p[d]) / s_sh[d];
    out[CTRL_OFF + (size_t)(r0 + r) * NSTE * DIM_D + (size_t)(NSTE - 1) * DIM_D + d] = 0.0f;
  }
  if (tid < ROWS) { hDl[tid] = x0p[DIM_D] / dp_sh; fl[tid] = 0.0f; }

  // ---------------- per-wave constants + weight fragments in VGPRs ----------------
  const int wv = tid >> 6;       // wave 0..7 -> N-tiles {2wv, 2wv+1}
  const int ln = tid & 63;
  const int lr = ln & 15;        // A-row / B-col within 16-tile
  const int g  = ln >> 4;        // 0..3
  const int lk8 = g * 8;         // k element offset within K-step

  bf16x8 w1f[2][3], w2f[2][8], w3f[2][8], w4f[2];
#pragma unroll
  for (int t = 0; t < 2; ++t) {
    const int n1 = wv * 32 + t * 16 + lr;
#pragma unroll
    for (int ks = 0; ks < 3; ++ks)
      w1f[t][ks] = *(const bf16x8*)(ws + W1B_OFF + n1 * 96 + ks * 32 + lk8);
#pragma unroll
    for (int ks = 0; ks < 8; ++ks) {
      w2f[t][ks] = *(const bf16x8*)(ws + W2B_OFF + n1 * 256 + ks * 32 + lk8);
      w3f[t][ks] = *(const bf16x8*)(ws + W3B_OFF + n1 * 256 + ks * 32 + lk8);
    }
  }
  {
    const int t4 = wv >> 2, kc = wv & 3;
#pragma unroll
    for (int ks2 = 0; ks2 < 2; ++ks2)
      w4f[ks2] = *(const bf16x8*)(ws + W4B_OFF + (t4 * 16 + lr) * 256 + (kc * 2 + ks2) * 32 + lk8);
  }
  const float bb1_0 = b1[wv * 32 + lr], bb1_1 = b1[wv * 32 + 16 + lr];
  const float bb2_0 = b2[wv * 32 + lr], bb2_1 = b2[wv * 32 + 16 + lr];
  const float bb3_0 = b3[wv * 32 + lr], bb3_1 = b3[wv * 32 + 16 + lr];
  const float b4d = b4[tid & 31];
  const int er = tid >> 5, ed = tid & 31;   // epilogue (row, dim)
  __syncthreads();

  // ---------------- 99 steps ----------------
  for (int n = 0; n < NSTE - 1; ++n) {
    // ---- L1: xb(K=96) -> actA ----
    {
      f32x4 a0 = {bb1_0, bb1_0, bb1_0, bb1_0};
      f32x4 a1 = {bb1_1, bb1_1, bb1_1, bb1_1};
#pragma unroll
      for (int ks = 0; ks < 3; ++ks) {
        bf16x8 af = *(const bf16x8*)(xbB + swz256(lr, ks * 64 + g * 16));
        a0 = mfma16(af, w1f[0][ks], a0);
        a1 = mfma16(af, w1f[1][ks], a1);
      }
#pragma unroll
      for (int q = 0; q < 4; ++q) {
        int row = g * 4 + q;
        *(__bf16*)(aAB + swz512(row, (wv * 32 + lr) * 2))      = (__bf16)fmaxf(a0[q], 0.0f);
        *(__bf16*)(aAB + swz512(row, (wv * 32 + 16 + lr) * 2)) = (__bf16)fmaxf(a1[q], 0.0f);
      }
    }
    __syncthreads();
    // ---- L2: actA -> actB ----
    {
      f32x4 a0 = {bb2_0, bb2_0, bb2_0, bb2_0};
      f32x4 a1 = {bb2_1, bb2_1, bb2_1, bb2_1};
#pragma unroll
      for (int ks = 0; ks < 8; ++ks) {
        bf16x8 af = *(const bf16x8*)(aAB + swz512(lr, ks * 64 + g * 16));
        a0 = mfma16(af, w2f[0][ks], a0);
        a1 = mfma16(af, w2f[1][ks], a1);
      }
#pragma unroll
      for (int q = 0; q < 4; ++q) {
        int row = g * 4 + q;
        *(__bf16*)(aBB + swz512(row, (wv * 32 + lr) * 2))      = (__bf16)fmaxf(a0[q], 0.0f);
        *(__bf16*)(aBB + swz512(row, (wv * 32 + 16 + lr) * 2)) = (__bf16)fmaxf(a1[q], 0.0f);
      }
    }
    __syncthreads();
    // ---- L3: actB -> actA ----
    {
      f32x4 a0 = {bb3_0, bb3_0, bb3_0, bb3_0};
      f32x4 a1 = {bb3_1, bb3_1, bb3_1, bb3_1};
#pragma unroll
      for (int ks = 0; ks < 8; ++ks) {
        bf16x8 af = *(const bf16x8*)(aBB + swz512(lr, ks * 64 + g * 16));
        a0 = mfma16(af, w3f[0][ks], a0);
        a1 = mfma16(af, w3f[1][ks], a1);
      }
#pragma unroll
      for (int q = 0; q < 4; ++q) {
        int row = g * 4 + q;
        *(__bf16*)(aAB + swz512(row, (wv * 32 + lr) * 2))      = (__bf16)fmaxf(a0[q], 0.0f);
        *(__bf16*)(aAB + swz512(row, (wv * 32 + 16 + lr) * 2)) = (__bf16)fmaxf(a1[q], 0.0f);
      }
    }
    __syncthreads();
    // ---- L4: actA -> psum (K split across waves: wv>>2 = tile, wv&3 = K-chunk) ----
    {
      const int kc = wv & 3;
      f32x4 a4 = {0.0f, 0.0f, 0.0f, 0.0f};
#pragma unroll
      for (int ks2 = 0; ks2 < 2; ++ks2) {
        const int ks = kc * 2 + ks2;
        bf16x8 af = *(const bf16x8*)(aAB + swz512(lr, ks * 64 + g * 16));
        a4 = mfma16(af, w4f[ks2], a4);
      }
#pragma unroll
      for (int q = 0; q < 4; ++q) psum[wv][g * 4 + q][lr] = a4[q];
    }
    if (tid < ROWS) {            // f += sum(V_old) * DT (pre-update x)
      float s = 0.0f;
#pragma unroll
      for (int d = 0; d < DIM_D; ++d) s += xVf[tid][d];
      fl[tid] += s * DT_C;
    }
    __syncthreads();
    // ---- epilogue: u = sigmoid(b4 + sum psum), RNG, state update ----
    {
      const int r = er, d = ed;
      float up = b4d;
      const int g0 = (d >> 4) * 4, c = d & 15;
#pragma unroll
      for (int w2 = 0; w2 < 4; ++w2) up += psum[g0 + w2][r][c];
      const float u = 1.0f / (1.0f + expf(-up));
      out[CTRL_OFF + (size_t)(r0 + r) * NSTE * DIM_D + (size_t)n * DIM_D + d] = u;

      const uint32_t F = (uint32_t)((r0 + r) * DIM_D + d);
      uint32_t o0, o1;
      tf2x32(keys[n][0], keys[n][1], 0u, F, o0, o1);
      const uint32_t bits = o0 ^ o1;
      const float uf = __uint_as_float((bits >> 9) | 0x3f800000u) - 1.0f;
      const bool jump = uf < 0.05f;

      float hv = jump ? 0.0f : (hVl[r][d] + DT_C);
      hVl[r][d] = hv;
      float cr = crf[r][d] + (jump ? u : 0.0f);
      crf[r][d] = cr;
      float V = 1.0f - expf(-s_sh[d] * hv);
      xVf[r][d] = V;

      const size_t xo = X_OFF + (size_t)(r0 + r) * NSTE * 65 + (size_t)(n + 1) * 65;
      out[xo + d] = V;
      out[xo + 33 + d] = cr;
      *(__bf16*)(xbB + swz256(r, d * 2))        = (__bf16)V;
      *(__bf16*)(xbB + swz256(r, (33 + d) * 2)) = (__bf16)cr;
      if (d == 0) {
        float hd = hDl[r] + DT_C; hDl[r] = hd;
        float Dv = dp_sh * hd;
        out[xo + 32] = Dv;
        *(__bf16*)(xbB + swz256(r, 64))  = (__bf16)Dv;                      // col 32
        *(__bf16*)(xbB + swz256(r, 130)) = (__bf16)(DT_C * (float)(n + 1)); // col 65 = t
      }
    }
    __syncthreads();
  }

  // ---- J = f + sum(CR_last) ----
  if (tid < ROWS) {
    float s = 0.0f;
#pragma unroll
    for (int d = 0; d < DIM_D; ++d) s += crf[tid][d];
    out[J_OFF + (size_t)(r0 + tid)] = fl[tid] + s;
  }
}

extern "C" void kernel_launch(void* const* d_in, const int* in_sizes, int n_in,
                              void* d_out, int out_size, void* d_ws, size_t ws_size,
                              hipStream_t stream) {
  const float* W1 = (const float*)d_in[0];
  const float* b1 = (const float*)d_in[1];
  const float* W2 = (const float*)d_in[2];
  const float* b2 = (const float*)d_in[3];
  const float* W3 = (const float*)d_in[4];
  const float* b3 = (const float*)d_in[5];
  const float* W4 = (const float*)d_in[6];
  const float* b4 = (const float*)d_in[7];
  const float* x0 = (const float*)d_in[8];
  const float* s  = (const float*)d_in[9];
  const float* dp = (const float*)d_in[10];
  __bf16* ws = (__bf16*)d_ws;
  float* out = (float*)d_out;

  hipLaunchKernelGGL(conv_w, dim3(WS_ELEMS / 256), dim3(256), 0, stream, W1, W2, W3, W4, ws);
  hipLaunchKernelGGL(model_kernel, dim3(NBLK), dim3(BLKT), 0, stream,
                     ws, b1, b2, b3, b4, x0, s, dp, out);
}